// Round 1
// baseline (323.545 us; speedup 1.0000x reference)
//
#include <hip/hip_runtime.h>

#define HID 896
#define NH 14
#define NKV 2
#define NREP 7
#define SEQ 2048
#define BT 2
#define NTOK (BT*SEQ)
#define LOG2E 1.4426950408889634f

typedef __attribute__((ext_vector_type(8))) short bf16x8;      // 8 bf16 (guide-verified frag type)
typedef __attribute__((ext_vector_type(8))) unsigned short u16x8;
typedef __attribute__((ext_vector_type(4))) float fx4;

__device__ __forceinline__ unsigned short f2b(float x){
  union { float f; unsigned u; } a; a.f = x;
  unsigned r = a.u + 0x7FFFu + ((a.u >> 16) & 1u);   // RNE
  return (unsigned short)(r >> 16);
}

// ---------------- fused QKV projection + bias + RoPE ----------------
// grid (NTOK/64, 18), block 256. bn 0..13 -> Q head bn; 14,15 -> K; 16,17 -> V
__global__ __launch_bounds__(256) void qkv_rope_kernel(
    const float* __restrict__ hidden, const int* __restrict__ pos,
    const float* __restrict__ Wq, const float* __restrict__ bq,
    const float* __restrict__ Wk, const float* __restrict__ bk,
    const float* __restrict__ Wv, const float* __restrict__ bv,
    unsigned short* __restrict__ qo, unsigned short* __restrict__ ko,
    unsigned short* __restrict__ vo)
{
  __shared__ short As[64*40];   // 64 rows x 32 k, stride 40 (16B-aligned rows, 2-way banks)
  __shared__ short Bs[64*40];
  const int tid = threadIdx.x;
  const int bm = blockIdx.x, bn = blockIdx.y;
  const int w = tid >> 6, l = tid & 63, l15 = l & 15, l16 = l >> 4;

  const float *W, *bias; int kind, hloc;
  if (bn < NH)      { W = Wq + (size_t)bn*64*HID;      bias = bq + bn*64;      kind = 0; hloc = bn; }
  else if (bn < 16) { W = Wk + (size_t)(bn-NH)*64*HID; bias = bk + (bn-NH)*64; kind = 1; hloc = bn-NH; }
  else              { W = Wv + (size_t)(bn-16)*64*HID; bias = bv + (bn-16)*64; kind = 2; hloc = bn-16; }

  fx4 acc[4] = {{0,0,0,0},{0,0,0,0},{0,0,0,0},{0,0,0,0}};

  const int r = tid >> 2, c8 = (tid & 3) * 8;
  const float* ap0 = hidden + (size_t)(bm*64 + r)*HID + c8;
  const float* bp0 = W + (size_t)r*HID + c8;

  for (int kc = 0; kc < HID; kc += 32){
    __syncthreads();
    float4 a0 = *(const float4*)(ap0 + kc);
    float4 a1 = *(const float4*)(ap0 + kc + 4);
    float4 b0 = *(const float4*)(bp0 + kc);
    float4 b1 = *(const float4*)(bp0 + kc + 4);
    bf16x8 avv, bvv;
    avv[0]=(short)f2b(a0.x); avv[1]=(short)f2b(a0.y); avv[2]=(short)f2b(a0.z); avv[3]=(short)f2b(a0.w);
    avv[4]=(short)f2b(a1.x); avv[5]=(short)f2b(a1.y); avv[6]=(short)f2b(a1.z); avv[7]=(short)f2b(a1.w);
    bvv[0]=(short)f2b(b0.x); bvv[1]=(short)f2b(b0.y); bvv[2]=(short)f2b(b0.z); bvv[3]=(short)f2b(b0.w);
    bvv[4]=(short)f2b(b1.x); bvv[5]=(short)f2b(b1.y); bvv[6]=(short)f2b(b1.z); bvv[7]=(short)f2b(b1.w);
    *(bf16x8*)&As[r*40 + c8] = avv;
    *(bf16x8*)&Bs[r*40 + c8] = bvv;
    __syncthreads();
    bf16x8 af = *(bf16x8*)&As[(w*16 + l15)*40 + l16*8];
#pragma unroll
    for (int nt = 0; nt < 4; nt++){
      bf16x8 bfr = *(bf16x8*)&Bs[(nt*16 + l15)*40 + l16*8];
      acc[nt] = __builtin_amdgcn_mfma_f32_16x16x32_bf16(af, bfr, acc[nt], 0, 0, 0);
    }
  }

  float bl[4];
#pragma unroll
  for (int nt = 0; nt < 4; nt++) bl[nt] = bias[nt*16 + l15];

  if (kind == 2){
#pragma unroll
    for (int j = 0; j < 4; j++){
      int grow = bm*64 + w*16 + l16*4 + j;           // C/D row = (lane>>4)*4 + reg
      int b = grow >> 11, s = grow & (SEQ-1);
      unsigned short* dst = vo + ((size_t)(b*NKV + hloc)*SEQ + s)*64;
#pragma unroll
      for (int nt = 0; nt < 4; nt++)
        dst[nt*16 + l15] = f2b(acc[nt][j] + bl[nt]);
    }
  } else {
    // RoPE: pairs (d, d+32) = (acc[nt], acc[nt+2]) same lane. inv_freq = 2^(-d*log2(1e6)/32)
    float invf[2];
#pragma unroll
    for (int nt = 0; nt < 2; nt++)
      invf[nt] = exp2f(-(float)(nt*16 + l15) * 0.62286151779138041f);
#pragma unroll
    for (int j = 0; j < 4; j++){
      int grow = bm*64 + w*16 + l16*4 + j;
      int b = grow >> 11, s = grow & (SEQ-1);
      float p = (float)pos[grow];
      unsigned short* dst = (kind == 0)
          ? qo + ((size_t)(b*NH  + hloc)*SEQ + s)*64
          : ko + ((size_t)(b*NKV + hloc)*SEQ + s)*64;
#pragma unroll
      for (int nt = 0; nt < 2; nt++){
        int d = nt*16 + l15;
        float f = p * invf[nt];
        float sv, cv;
        sincosf(f, &sv, &cv);
        float x1 = acc[nt][j]   + bl[nt];
        float x2 = acc[nt+2][j] + bl[nt+2];
        dst[d]    = f2b(x1*cv - x2*sv);
        dst[d+32] = f2b(x2*cv + x1*sv);
      }
    }
  }
}

// ---------------- flash attention (causal, GQA) ----------------
// grid (SEQ/64, NH, BT), block 256. Wave w owns q-rows [bq0+16w, bq0+16w+16).
__device__ __forceinline__ int voff(int d){ return d*40 + ((d>>3)<<3); }  // padded V^T row offset

__global__ __launch_bounds__(256) void attn_kernel(
    const unsigned short* __restrict__ q, const unsigned short* __restrict__ k,
    const unsigned short* __restrict__ v, unsigned short* __restrict__ ao)
{
  __shared__ short Ks[32*72];       // 32 keys x 64 d, stride 72
  __shared__ short Vt[64*40 + 64];  // V^T: 64 d x 32 keys, padded (voff)
  __shared__ short Ps[4][16*40];    // per-wave P round-trip (C-layout -> A-layout)

  const int tid = threadIdx.x;
  const int w = tid >> 6, l = tid & 63, l15 = l & 15, l16 = l >> 4;
  const int bq0 = blockIdx.x*64, h = blockIdx.y, b = blockIdx.z, kvh = h / NREP;

  const int qrow = bq0 + w*16 + l15;                 // A-operand m = lane&15
  const unsigned short* qp = q + ((size_t)(b*NH + h)*SEQ + qrow)*64;
  bf16x8 qf0 = *(const bf16x8*)(qp + l16*8);         // dims 0..31
  bf16x8 qf1 = *(const bf16x8*)(qp + 32 + l16*8);    // dims 32..63

  fx4 o[4] = {{0,0,0,0},{0,0,0,0},{0,0,0,0},{0,0,0,0}};
  float m_run[4] = {-1e30f,-1e30f,-1e30f,-1e30f};
  float l_run[4] = {0.f,0.f,0.f,0.f};

  const int ntiles = bq0/32 + 2;
  const int sr = tid >> 3, sc = (tid & 7)*8;
  const unsigned short* kbase = k + ((size_t)(b*NKV + kvh)*SEQ)*64;
  const unsigned short* vbase = v + ((size_t)(b*NKV + kvh)*SEQ)*64;

  for (int kt = 0; kt < ntiles; kt++){
    __syncthreads();
    u16x8 kv8 = *(const u16x8*)(kbase + (size_t)(kt*32 + sr)*64 + sc);
    *(u16x8*)&Ks[sr*72 + sc] = kv8;
    u16x8 vv8 = *(const u16x8*)(vbase + (size_t)(kt*32 + sr)*64 + sc);
#pragma unroll
    for (int i = 0; i < 8; i++) Vt[voff(sc + i) + sr] = (short)vv8[i];
    __syncthreads();

    // S = Q K^T  (16 q-rows x 32 keys per wave)
    fx4 s0 = {0,0,0,0}, s1 = {0,0,0,0};
    {
      bf16x8 k00 = *(bf16x8*)&Ks[l15*72 + l16*8];
      bf16x8 k01 = *(bf16x8*)&Ks[l15*72 + 32 + l16*8];
      s0 = __builtin_amdgcn_mfma_f32_16x16x32_bf16(qf0, k00, s0, 0,0,0);
      s0 = __builtin_amdgcn_mfma_f32_16x16x32_bf16(qf1, k01, s0, 0,0,0);
      bf16x8 k10 = *(bf16x8*)&Ks[(16+l15)*72 + l16*8];
      bf16x8 k11 = *(bf16x8*)&Ks[(16+l15)*72 + 32 + l16*8];
      s1 = __builtin_amdgcn_mfma_f32_16x16x32_bf16(qf0, k10, s1, 0,0,0);
      s1 = __builtin_amdgcn_mfma_f32_16x16x32_bf16(qf1, k11, s1, 0,0,0);
    }

    const int key0 = kt*32 + l15, key1 = key0 + 16;
    float alpha[4];
#pragma unroll
    for (int j = 0; j < 4; j++){
      int qg = bq0 + w*16 + l16*4 + j;
      float t0 = (key0 <= qg) ? s0[j]*0.125f : -1e30f;
      float t1 = (key1 <= qg) ? s1[j]*0.125f : -1e30f;
      float mx = fmaxf(t0, t1);
      mx = fmaxf(mx, __shfl_xor(mx, 1)); mx = fmaxf(mx, __shfl_xor(mx, 2));
      mx = fmaxf(mx, __shfl_xor(mx, 4)); mx = fmaxf(mx, __shfl_xor(mx, 8));
      float mn = fmaxf(m_run[j], mx);
      float al = exp2f((m_run[j] - mn)*LOG2E);
      m_run[j] = mn;
      float p0 = exp2f((t0 - mn)*LOG2E);
      float p1 = exp2f((t1 - mn)*LOG2E);
      float rs = p0 + p1;
      rs += __shfl_xor(rs, 1); rs += __shfl_xor(rs, 2);
      rs += __shfl_xor(rs, 4); rs += __shfl_xor(rs, 8);
      l_run[j] = l_run[j]*al + rs;
      alpha[j] = al;
      Ps[w][(l16*4 + j)*40 + l15]      = (short)f2b(p0);
      Ps[w][(l16*4 + j)*40 + 16 + l15] = (short)f2b(p1);
    }
#pragma unroll
    for (int nt = 0; nt < 4; nt++)
#pragma unroll
      for (int j = 0; j < 4; j++) o[nt][j] *= alpha[j];

    asm volatile("s_waitcnt lgkmcnt(0)" ::: "memory");  // cross-lane LDS visibility within wave
    bf16x8 pa = *(bf16x8*)&Ps[w][l15*40 + l16*8];       // P in A-layout
#pragma unroll
    for (int nt = 0; nt < 4; nt++){
      bf16x8 vb = *(bf16x8*)&Vt[voff(nt*16 + l15) + l16*8];  // B[k=key][n=dim] = V^T rows
      o[nt] = __builtin_amdgcn_mfma_f32_16x16x32_bf16(pa, vb, o[nt], 0,0,0);
    }
  }

#pragma unroll
  for (int j = 0; j < 4; j++){
    int qg = bq0 + w*16 + l16*4 + j;
    float inv = 1.0f / l_run[j];
    unsigned short* dst = ao + ((size_t)(b*SEQ + qg))*HID + h*64;
#pragma unroll
    for (int nt = 0; nt < 4; nt++)
      dst[nt*16 + l15] = f2b(o[nt][j] * inv);
  }
}

// ---------------- output projection: attn(bf16) @ Wo^T -> fp32 ----------------
// grid (NTOK/64, 14), block 256
__global__ __launch_bounds__(256) void out_gemm_kernel(
    const unsigned short* __restrict__ A, const float* __restrict__ Wo,
    float* __restrict__ out)
{
  __shared__ short As[64*40];
  __shared__ short Bs[64*40];
  const int tid = threadIdx.x;
  const int bm = blockIdx.x, bn = blockIdx.y;
  const int w = tid >> 6, l = tid & 63, l15 = l & 15, l16 = l >> 4;

  fx4 acc[4] = {{0,0,0,0},{0,0,0,0},{0,0,0,0},{0,0,0,0}};
  const int r = tid >> 2, c8 = (tid & 3)*8;
  const unsigned short* ap0 = A + (size_t)(bm*64 + r)*HID + c8;
  const float* bp0 = Wo + (size_t)(bn*64 + r)*HID + c8;

  for (int kc = 0; kc < HID; kc += 32){
    __syncthreads();
    u16x8 a8 = *(const u16x8*)(ap0 + kc);
    float4 b0 = *(const float4*)(bp0 + kc);
    float4 b1 = *(const float4*)(bp0 + kc + 4);
    bf16x8 bvv;
    bvv[0]=(short)f2b(b0.x); bvv[1]=(short)f2b(b0.y); bvv[2]=(short)f2b(b0.z); bvv[3]=(short)f2b(b0.w);
    bvv[4]=(short)f2b(b1.x); bvv[5]=(short)f2b(b1.y); bvv[6]=(short)f2b(b1.z); bvv[7]=(short)f2b(b1.w);
    *(u16x8*)&As[r*40 + c8] = a8;
    *(bf16x8*)&Bs[r*40 + c8] = bvv;
    __syncthreads();
    bf16x8 af = *(bf16x8*)&As[(w*16 + l15)*40 + l16*8];
#pragma unroll
    for (int nt = 0; nt < 4; nt++){
      bf16x8 bfr = *(bf16x8*)&Bs[(nt*16 + l15)*40 + l16*8];
      acc[nt] = __builtin_amdgcn_mfma_f32_16x16x32_bf16(af, bfr, acc[nt], 0, 0, 0);
    }
  }

#pragma unroll
  for (int j = 0; j < 4; j++){
    int grow = bm*64 + w*16 + l16*4 + j;
    float* dst = out + (size_t)grow*HID + bn*64;
#pragma unroll
    for (int nt = 0; nt < 4; nt++)
      dst[nt*16 + l15] = acc[nt][j];
  }
}

extern "C" void kernel_launch(void* const* d_in, const int* in_sizes, int n_in,
                              void* d_out, int out_size, void* d_ws, size_t ws_size,
                              hipStream_t stream)
{
  const float* hidden = (const float*)d_in[0];
  const int*   pos    = (const int*)d_in[1];      // jax default x64-disabled -> int32
  const float* Wq = (const float*)d_in[2]; const float* bq = (const float*)d_in[3];
  const float* Wk = (const float*)d_in[4]; const float* bk = (const float*)d_in[5];
  const float* Wv = (const float*)d_in[6]; const float* bv = (const float*)d_in[7];
  const float* Wo = (const float*)d_in[8];

  unsigned short* qws = (unsigned short*)d_ws;                       // (B,NH,S,64) bf16
  unsigned short* kws = qws + (size_t)BT*NH*SEQ*64;                  // (B,NKV,S,64)
  unsigned short* vws = kws + (size_t)BT*NKV*SEQ*64;
  unsigned short* aws = vws + (size_t)BT*NKV*SEQ*64;                 // (B,S,896) bf16

  qkv_rope_kernel<<<dim3(NTOK/64, 18), 256, 0, stream>>>(
      hidden, pos, Wq, bq, Wk, bk, Wv, bv, qws, kws, vws);
  attn_kernel<<<dim3(SEQ/64, NH, BT), 256, 0, stream>>>(qws, kws, vws, aws);
  out_gemm_kernel<<<dim3(NTOK/64, NH), 256, 0, stream>>>(aws, Wo, (float*)d_out);
}